// Round 7
// baseline (219.210 us; speedup 1.0000x reference)
//
#include <hip/hip_runtime.h>

#define B_ 2048
#define T_ 200
#define D_ 64
#define NP 192  // per (b,t): [r_x(64) | u_x(64) | c_x(64)] fp16

constexpr int TCHUNK = 40;  // t-chunk per block in kernel 1 (5 chunks over T=200)

typedef _Float16 half_t;
typedef __attribute__((ext_vector_type(2))) _Float16 h2;
typedef __attribute__((ext_vector_type(8))) _Float16 h8;

#if defined(__has_builtin)
#if __has_builtin(__builtin_amdgcn_fdot2)
#define HAS_FDOT2 1
#endif
#endif

__device__ __forceinline__ float dot2f(h2 a, h2 b, float c) {
#ifdef HAS_FDOT2
  return __builtin_amdgcn_fdot2(a, b, c, false);
#else
  return fmaf((float)a[0], (float)b[0], fmaf((float)a[1], (float)b[1], c));
#endif
}

__device__ __forceinline__ h2 pick(h8 v, int i) {  // i is a literal at call sites
  h2 r;
  r[0] = v[2 * i];
  r[1] = v[2 * i + 1];
  return r;
}

__device__ __forceinline__ h2 mkh2(float a, float b) {
  h2 r;
  r[0] = (half_t)a;
  r[1] = (half_t)b;
  return r;
}

__device__ __forceinline__ float sigmoidf_(float x) {
  return 1.0f / (1.0f + __expf(-x));
}
__device__ __forceinline__ float tanhf_(float x) {
  x = fminf(fmaxf(x, -15.0f), 15.0f);
  float e = __expf(2.0f * x);
  return (e - 1.0f) / (e + 1.0f);
}

// X-macro: 32 (index, 2*index) pairs. All weight regs are NAMED SCALARS —
// rule #20: local arrays written in loops get demoted to scratch (SROA runs
// before unrolling); rounds 2-6 were silently reloading weights every step
// (VGPR_Count 88-128 << the ~160 needed). Named scalars have static accesses
// only, so they MUST live in VGPRs.
#define REP32(F) \
  F(0,0) F(1,2) F(2,4) F(3,6) F(4,8) F(5,10) F(6,12) F(7,14) \
  F(8,16) F(9,18) F(10,20) F(11,22) F(12,24) F(13,26) F(14,28) F(15,30) \
  F(16,32) F(17,34) F(18,36) F(19,38) F(20,40) F(21,42) F(22,44) F(23,46) \
  F(24,48) F(25,50) F(26,52) F(27,54) F(28,56) F(29,58) F(30,60) F(31,62)

// ---------------- Kernel 1: x-part preactivations (batch-parallel GEMV) ----
__global__ __launch_bounds__(64)
__attribute__((amdgpu_waves_per_eu(1))) void augru_xpre(
    const float* __restrict__ X, const int* __restrict__ SL,
    const float* __restrict__ Wg, const float* __restrict__ bg,
    const float* __restrict__ Wc, const float* __restrict__ bc,
    half_t* __restrict__ XP) {
  __shared__ __align__(16) half_t sX[8][64];

  const int d = threadIdx.x;        // 0..63
  const int chunk = blockIdx.x;     // 0..4
  const int b = blockIdx.y;         // 0..B-1
  const int L = SL[b];
  const int t0 = chunk * TCHUNK;
  if (t0 >= L) return;              // Xp past L is never read
  const int tend = (t0 + TCHUNK < L) ? t0 + TCHUNK : L;

  // x-part weight columns (rows k=0..63) as 96 named h2 scalars.
#define DECLX(I, K) h2 wxr##I, wxu##I, wxc##I;
  REP32(DECLX)
#undef DECLX
#define INITX(I, K)                                                  \
  wxr##I = mkh2(Wg[(K)*128 + d], Wg[(K + 1) * 128 + d]);             \
  wxu##I = mkh2(Wg[(K)*128 + 64 + d], Wg[(K + 1) * 128 + 64 + d]);   \
  wxc##I = mkh2(Wc[(K)*64 + d], Wc[(K + 1) * 64 + d]);
  REP32(INITX)
#undef INITX

  const float bgr = bg[d];
  const float bgu = bg[64 + d];
  const float bcd = bc[d];

  const float* __restrict__ xrow = X + (size_t)b * (T_ * D_);
  half_t* __restrict__ xp = XP + (size_t)b * (T_ * NP);
  const int rr = d >> 3;            // staging row this lane loads
  const int c8 = (d & 7) * 8;       // staging col offset (8 floats)
  const h8* __restrict__ px = (const h8*)&sX[0][0];

  for (int ts = t0; ts < tend; ts += 8) {
    // Stage rows ts..ts+7 (in-bounds: ts+7 < t0+TCHUNK <= T).
    const float4 fa = *(const float4*)(xrow + (ts + rr) * D_ + c8);
    const float4 fb = *(const float4*)(xrow + (ts + rr) * D_ + c8 + 4);
    h8 hv;
    hv[0] = (half_t)fa.x; hv[1] = (half_t)fa.y;
    hv[2] = (half_t)fa.z; hv[3] = (half_t)fa.w;
    hv[4] = (half_t)fb.x; hv[5] = (half_t)fb.y;
    hv[6] = (half_t)fb.z; hv[7] = (half_t)fb.w;
    *(h8*)(&sX[rr][c8]) = hv;
    asm volatile("" ::: "memory");  // same-wave DS pipe is in-order

#pragma unroll
    for (int r = 0; r < 8; ++r) {   // r is runtime-ish but px[] is LDS: fine
      const int t = ts + r;
      if (t >= tend) break;         // wave-uniform
      float r0 = bgr, r1 = 0.f, u0 = bgu, u1 = 0.f, c0 = bcd, c1 = 0.f;
#define XQ(Q, I0, I1, I2, I3)                        \
  {                                                  \
    const h8 xb = px[r * 8 + Q];                     \
    r0 = dot2f(pick(xb, 0), wxr##I0, r0);            \
    r1 = dot2f(pick(xb, 1), wxr##I1, r1);            \
    r0 = dot2f(pick(xb, 2), wxr##I2, r0);            \
    r1 = dot2f(pick(xb, 3), wxr##I3, r1);            \
    u0 = dot2f(pick(xb, 0), wxu##I0, u0);            \
    u1 = dot2f(pick(xb, 1), wxu##I1, u1);            \
    u0 = dot2f(pick(xb, 2), wxu##I2, u0);            \
    u1 = dot2f(pick(xb, 3), wxu##I3, u1);            \
    c0 = dot2f(pick(xb, 0), wxc##I0, c0);            \
    c1 = dot2f(pick(xb, 1), wxc##I1, c1);            \
    c0 = dot2f(pick(xb, 2), wxc##I2, c0);            \
    c1 = dot2f(pick(xb, 3), wxc##I3, c1);            \
  }
      XQ(0, 0, 1, 2, 3)
      XQ(1, 4, 5, 6, 7)
      XQ(2, 8, 9, 10, 11)
      XQ(3, 12, 13, 14, 15)
      XQ(4, 16, 17, 18, 19)
      XQ(5, 20, 21, 22, 23)
      XQ(6, 24, 25, 26, 27)
      XQ(7, 28, 29, 30, 31)
#undef XQ
      half_t* o = xp + (size_t)t * NP;
      o[d] = (half_t)(r0 + r1);
      o[64 + d] = (half_t)(u0 + u1);
      o[128 + d] = (half_t)(c0 + c1);
    }
    asm volatile("" ::: "memory");  // keep next staging write after these reads
  }
}

// ---------------- Kernel 2: recurrence (h-part only) ----------------------
__global__ __launch_bounds__(64)
__attribute__((amdgpu_waves_per_eu(1))) void augru_rec(
    const half_t* __restrict__ XP, const int* __restrict__ SL,
    const float* __restrict__ ATT, const float* __restrict__ Wg,
    const float* __restrict__ Wc, float* __restrict__ OUT) {
  __shared__ __align__(16) half_t sH[64];
  __shared__ __align__(16) half_t sR[64];

  const int d = threadIdx.x;  // one wave per block, one batch row
  const int b = blockIdx.x;

  // h-part weight columns (rows k=64..127) as 96 named h2 scalars.
#define DECLW(I, K) h2 wr##I, wu##I, wcc##I;
  REP32(DECLW)
#undef DECLW
#define INITW(I, K)                                                          \
  wr##I = mkh2(Wg[(64 + K) * 128 + d], Wg[(65 + K) * 128 + d]);              \
  wu##I = mkh2(Wg[(64 + K) * 128 + 64 + d], Wg[(65 + K) * 128 + 64 + d]);    \
  wcc##I = mkh2(Wc[(64 + K) * 64 + d], Wc[(65 + K) * 64 + d]);
  REP32(INITW)
#undef INITW

  const int L = SL[b];  // >= 1
  const half_t* __restrict__ xp = XP + (size_t)b * (T_ * NP);
  const float* __restrict__ arow = ATT + (size_t)b * T_;
  float* __restrict__ orow = OUT + (size_t)b * (T_ * D_);
  const h8* __restrict__ ph = (const h8*)sH;
  const h8* __restrict__ pr = (const h8*)sR;

  // h broadcast registers: 8 named h8 (32 VGPRs). h0 = 0.
  h8 hb0, hb1, hb2, hb3, hb4, hb5, hb6, hb7;
  {
    h8 z;
#pragma unroll
    for (int i = 0; i < 8; ++i) z[i] = (half_t)0.f;
    hb0 = z; hb1 = z; hb2 = z; hb3 = z; hb4 = z; hb5 = z; hb6 = z; hb7 = z;
  }

  // 2-deep prefetch rotation for Xp triplet and att.
  half_t xr0 = xp[d], xu0 = xp[64 + d], xc0 = xp[128 + d];
  float a0 = arow[0];
  const int i1 = (1 < L) ? 1 : 0;
  half_t xr1 = xp[i1 * NP + d], xu1 = xp[i1 * NP + 64 + d],
         xc1 = xp[i1 * NP + 128 + d];
  float a1 = arow[i1];

  float h = 0.0f;

  for (int t = 0; t < L; ++t) {
    // Prefetch t+2 (clamped; hidden under the dot chains).
    const int t2 = (t + 2 < L) ? t + 2 : (L - 1);
    const half_t tr = xp[t2 * NP + d];
    const half_t tu = xp[t2 * NP + 64 + d];
    const half_t tc = xp[t2 * NP + 128 + d];
    const float ta = arow[t2];

    // ---- r gate (critical path) + u gate, from in-register hb ----
    float ar0 = (float)xr0, ar1 = 0.f, au0 = (float)xu0, au1 = 0.f;
#define GQ(Q, I0, I1, I2, I3)                      \
  ar0 = dot2f(pick(hb##Q, 0), wr##I0, ar0);        \
  ar1 = dot2f(pick(hb##Q, 1), wr##I1, ar1);        \
  ar0 = dot2f(pick(hb##Q, 2), wr##I2, ar0);        \
  ar1 = dot2f(pick(hb##Q, 3), wr##I3, ar1);        \
  au0 = dot2f(pick(hb##Q, 0), wu##I0, au0);        \
  au1 = dot2f(pick(hb##Q, 1), wu##I1, au1);        \
  au0 = dot2f(pick(hb##Q, 2), wu##I2, au0);        \
  au1 = dot2f(pick(hb##Q, 3), wu##I3, au1);
    GQ(0, 0, 1, 2, 3)
    GQ(1, 4, 5, 6, 7)
    GQ(2, 8, 9, 10, 11)
    GQ(3, 12, 13, 14, 15)
    GQ(4, 16, 17, 18, 19)
    GQ(5, 20, 21, 22, 23)
    GQ(6, 24, 25, 26, 27)
    GQ(7, 28, 29, 30, 31)
#undef GQ
    const float r = sigmoidf_(ar0 + ar1);
    sR[d] = (half_t)(r * h);
    asm volatile("" ::: "memory");

    // u sigmoid + gate scale fill the sR write->read latency window.
    const float u = sigmoidf_(au0 + au1);
    const float ua = a0 * u;

    // ---- candidate from rh broadcast ----
    float ac0 = (float)xc0, ac1 = 0.f;
#define CQ(Q, I0, I1, I2, I3)                      \
  {                                                \
    const h8 rb = pr[Q];                           \
    ac0 = dot2f(pick(rb, 0), wcc##I0, ac0);        \
    ac1 = dot2f(pick(rb, 1), wcc##I1, ac1);        \
    ac0 = dot2f(pick(rb, 2), wcc##I2, ac0);        \
    ac1 = dot2f(pick(rb, 3), wcc##I3, ac1);        \
  }
    CQ(0, 0, 1, 2, 3)
    CQ(1, 4, 5, 6, 7)
    CQ(2, 8, 9, 10, 11)
    CQ(3, 12, 13, 14, 15)
    CQ(4, 16, 17, 18, 19)
    CQ(5, 20, 21, 22, 23)
    CQ(6, 24, 25, 26, 27)
    CQ(7, 28, 29, 30, 31)
#undef CQ
    const float c = tanhf_(ac0 + ac1);

    h = fmaf(ua, c - h, h);  // (1-ua)*h + ua*c

    // Stage h for the NEXT step; LDS latency hides under store + rotation.
    sH[d] = (half_t)h;
    asm volatile("" ::: "memory");
    hb0 = ph[0]; hb1 = ph[1]; hb2 = ph[2]; hb3 = ph[3];
    hb4 = ph[4]; hb5 = ph[5]; hb6 = ph[6]; hb7 = ph[7];

    orow[t * D_ + d] = h;

    xr0 = xr1; xu0 = xu1; xc0 = xc1; a0 = a1;
    xr1 = tr;  xu1 = tu;  xc1 = tc;  a1 = ta;
  }

  for (int t = L; t < T_; ++t) orow[t * D_ + d] = 0.0f;
}

// ---------------- Fallback (round-2 kernel, used only if ws too small) -----
constexpr int FWAVES = 4;
constexpr int FBLK = FWAVES * 64;
constexpr int FNBLK = B_ / FWAVES;

__global__ __launch_bounds__(FBLK, 2) void augru_dot2(
    const float* __restrict__ X, const int* __restrict__ SL,
    const float* __restrict__ ATT, const float* __restrict__ Wg,
    const float* __restrict__ bg, const float* __restrict__ Wc,
    const float* __restrict__ bc, float* __restrict__ OUT) {
  __shared__ __align__(16) half_t sV[FWAVES][192];

  const int tid = threadIdx.x;
  const int wave = tid >> 6;
  const int d = tid & 63;
  const int b = blockIdx.x * FWAVES + wave;

  h2 wr[64], wu[64], wc[64];
#pragma unroll
  for (int k2 = 0; k2 < 64; ++k2) {
    wr[k2] = mkh2(Wg[(2 * k2) * 128 + d], Wg[(2 * k2 + 1) * 128 + d]);
    wu[k2] = mkh2(Wg[(2 * k2) * 128 + 64 + d], Wg[(2 * k2 + 1) * 128 + 64 + d]);
    wc[k2] = mkh2(Wc[(2 * k2) * 64 + d], Wc[(2 * k2 + 1) * 64 + d]);
  }

  const float bgr = bg[d];
  const float bgu = bg[64 + d];
  const float bcd = bc[d];

  const int L = SL[b];
  const float* __restrict__ xrow = X + (size_t)b * (T_ * D_);
  const float* __restrict__ arow = ATT + (size_t)b * T_;
  float* __restrict__ orow = OUT + (size_t)b * (T_ * D_);

  half_t* __restrict__ vh = &sV[wave][0];
  const uint4* __restrict__ v4p = (const uint4*)vh;

  float h = 0.0f;
  float xn = xrow[d];
  float an = arow[0];

  for (int t = 0; t < L; ++t) {
    const float a_t = an;
    vh[d] = (half_t)xn;
    vh[64 + d] = (half_t)h;
    asm volatile("s_waitcnt lgkmcnt(0)" ::: "memory");

    const int tn = (t + 1 < L) ? t + 1 : t;
    const float xnn = xrow[tn * D_ + d];
    const float ann = arow[tn];

    float ar = bgr, au = bgu, ac = bcd;
#pragma unroll
    for (int q = 0; q < 16; ++q) {
      const uint4 blk = v4p[q];
      const h2 e0 = __builtin_bit_cast(h2, blk.x);
      const h2 e1 = __builtin_bit_cast(h2, blk.y);
      const h2 e2 = __builtin_bit_cast(h2, blk.z);
      const h2 e3 = __builtin_bit_cast(h2, blk.w);
      ar = dot2f(e0, wr[4 * q + 0], ar);
      ar = dot2f(e1, wr[4 * q + 1], ar);
      ar = dot2f(e2, wr[4 * q + 2], ar);
      ar = dot2f(e3, wr[4 * q + 3], ar);
      au = dot2f(e0, wu[4 * q + 0], au);
      au = dot2f(e1, wu[4 * q + 1], au);
      au = dot2f(e2, wu[4 * q + 2], au);
      au = dot2f(e3, wu[4 * q + 3], au);
      if (q < 8) {
        ac = dot2f(e0, wc[4 * q + 0], ac);
        ac = dot2f(e1, wc[4 * q + 1], ac);
        ac = dot2f(e2, wc[4 * q + 2], ac);
        ac = dot2f(e3, wc[4 * q + 3], ac);
      }
    }

    const float r = sigmoidf_(ar);
    const float u = sigmoidf_(au);

    vh[128 + d] = (half_t)(r * h);
    asm volatile("s_waitcnt lgkmcnt(0)" ::: "memory");

#pragma unroll
    for (int q = 0; q < 8; ++q) {
      const uint4 blk = v4p[16 + q];
      const h2 e0 = __builtin_bit_cast(h2, blk.x);
      const h2 e1 = __builtin_bit_cast(h2, blk.y);
      const h2 e2 = __builtin_bit_cast(h2, blk.z);
      const h2 e3 = __builtin_bit_cast(h2, blk.w);
      ac = dot2f(e0, wc[32 + 4 * q + 0], ac);
      ac = dot2f(e1, wc[32 + 4 * q + 1], ac);
      ac = dot2f(e2, wc[32 + 4 * q + 2], ac);
      ac = dot2f(e3, wc[32 + 4 * q + 3], ac);
    }

    const float c = tanhf_(ac);
    const float ua = a_t * u;
    h = fmaf(ua, c - h, h);
    orow[t * D_ + d] = h;

    xn = xnn;
    an = ann;
  }

  for (int t = L; t < T_; ++t) orow[t * D_ + d] = 0.0f;
}

extern "C" void kernel_launch(void* const* d_in, const int* in_sizes, int n_in,
                              void* d_out, int out_size, void* d_ws, size_t ws_size,
                              hipStream_t stream) {
  (void)in_sizes; (void)n_in; (void)out_size;
  const float* X  = (const float*)d_in[0];
  const int*   SL = (const int*)d_in[1];
  const float* A  = (const float*)d_in[2];
  const float* Wg = (const float*)d_in[3];
  const float* bg = (const float*)d_in[4];
  const float* Wc = (const float*)d_in[5];
  const float* bc = (const float*)d_in[6];
  float* O = (float*)d_out;

  const size_t need = (size_t)B_ * T_ * NP * sizeof(half_t);  // 157.3 MB
  if (ws_size >= need) {
    half_t* XP = (half_t*)d_ws;
    dim3 grid(T_ / TCHUNK, B_);
    augru_xpre<<<grid, 64, 0, stream>>>(X, SL, Wg, bg, Wc, bc, XP);
    augru_rec<<<B_, 64, 0, stream>>>(XP, SL, A, Wg, Wc, O);
  } else {
    augru_dot2<<<FNBLK, FBLK, 0, stream>>>(X, SL, A, Wg, bg, Wc, bc, O);
  }
}